// Round 20
// baseline (99.642 us; speedup 1.0000x reference)
//
#include <hip/hip_runtime.h>
#include <hip/hip_bf16.h>
#include <stdint.h>

// z_e (32,64,64,64) f32, codebook (512,64) f32.
// d_out (f32): [0..8388607] z_q (B,C,H,W); [8388608] loss; [8388609..] indices as float.
#define NPIX 131072
#define CDIM 64
#define KCODES 512
#define ZQ_SIZE 8388608
#define LOSS_OFF 8388608
#define IDXOUT_OFF 8388609
#define CH_STRIDE 4096
#define B_STRIDE 262144
#define MARGIN_UNITS 256       // 6.1e-5 gap (R6/R16-verified with 3-chain MFMA)
#define SCALE 4194304.0f       // 2^22
#define BIAS 0.5f

typedef __attribute__((ext_vector_type(8))) short short8v;   // 8 bf16
typedef __attribute__((ext_vector_type(16))) float f32x16;
typedef __attribute__((ext_vector_type(4))) float f32x4;
typedef __attribute__((ext_vector_type(4))) int i32x4;

// ws layout:
//   0       double loss
//   64      float  c2_ref[512]
//   2112    float  c2fix[512]
//   4160    ushort cb_hi chunks [g][code][8 bf16] scaled 2^11 (65536 B)
//   69696   ushort cb_lo chunks (65536 B)  — read from global/L2 (NOT staged)
//   135232  float  cbT[64][512] (131072 B)
#define WS_C2REF 64
#define WS_C2FIX 2112
#define WS_CBHI  4160
#define WS_CBLO  69696
#define WS_CBT   135232

// LDS layout (69.8 KB -> 2 blocks/CU; 2 x 8 waves = 16 waves/CU from 2
// INDEPENDENT blocks — one block's barrier stall no longer idles the CU):
#define L_CBHI  0          // 65536
#define L_C2F   65536      // 2048
#define L_QUEUE 67584      // int[256]
#define L_QCNT  68608      // int (+pad)
#define L_WLS   68672      // double[8]
#define L_IDXS  68736      // int[256]
#define LDS_SZ  69760

__device__ __forceinline__ uint32_t f2bf_rne(float v) {
    uint32_t u = __float_as_uint(v);
    return (u + 0x7FFFu + ((u >> 16) & 1u)) >> 16;
}
__device__ __forceinline__ float bf2f(short s) {
    return __uint_as_float(((uint32_t)(unsigned short)s) << 16);
}

__global__ void k0_prep(const float* __restrict__ cb, char* __restrict__ ws) {
#pragma clang fp contract(off)
    int k = blockIdx.x * 64 + threadIdx.x;
    if (k >= KCODES) return;
    const float* cr = cb + (size_t)k * CDIM;
    float r[8];
    #pragma unroll
    for (int j = 0; j < 8; ++j) r[j] = cr[j] * cr[j];
    #pragma unroll
    for (int t = 1; t < 8; ++t)
        #pragma unroll
        for (int j = 0; j < 8; ++j) r[j] += cr[8 * t + j] * cr[8 * t + j];
    ((float*)(ws + WS_C2REF))[k] = ((r[0] + r[1]) + (r[2] + r[3])) + ((r[4] + r[5]) + (r[6] + r[7]));
    float acc = 0.f;
    #pragma unroll
    for (int i = 0; i < CDIM; ++i) acc = fmaf(cr[i], cr[i], acc);
    ((float*)(ws + WS_C2FIX))[k] = (acc + BIAS) * SCALE;
    unsigned short* hi = (unsigned short*)(ws + WS_CBHI);
    unsigned short* lo = (unsigned short*)(ws + WS_CBLO);
    #pragma unroll
    for (int g = 0; g < 8; ++g)
        #pragma unroll
        for (int j = 0; j < 8; ++j) {
            float cs = cr[g * 8 + j] * 2048.0f;
            uint32_t uh = f2bf_rne(cs);
            float l = cs - bf2f((short)uh);
            size_t o = ((size_t)(g * KCODES + k)) * 8 + j;
            hi[o] = (unsigned short)uh;
            lo[o] = (unsigned short)f2bf_rne(l);
        }
    float* cbT = (float*)(ws + WS_CBT);
    #pragma unroll
    for (int i = 0; i < CDIM; ++i) cbT[i * KCODES + k] = cr[i];
}

// 512 threads = 8 waves, 256 contiguous pixels/block, 32 px/wave.
// Grid = 512 blocks = 2 blocks/CU. waves_per_eu(4,4) -> VGPR cap 128 (no spill).
__global__ __launch_bounds__(512)
__attribute__((amdgpu_waves_per_eu(4, 4)))
void k1_mfma(const float* __restrict__ z_e,
             const float* __restrict__ cb,
             char* __restrict__ ws,
             float* __restrict__ out) {
#pragma clang fp contract(off)
    extern __shared__ char smem[];
    int*    queue = (int*)(smem + L_QUEUE);
    int*    qcnt  = (int*)(smem + L_QCNT);
    double* wls   = (double*)(smem + L_WLS);
    int*    idxs  = (int*)(smem + L_IDXS);

    const int tid  = threadIdx.x;
    const int lane = tid & 63;
    const int wav  = tid >> 6;          // 0..7
    const int h    = lane >> 5;
    const int c    = lane & 31;

    const int pxblk = blockIdx.x * 256;
    const int b     = pxblk >> 12;
    const int hwb   = pxblk & 4095;
    const float* zb = z_e + (size_t)b * B_STRIDE;

    // ---- stage cb_hi (64KB) + c2fix (2KB) to LDS
    if (tid == 0) *qcnt = 0;
    {
        const uint4* src = (const uint4*)(ws + WS_CBHI);
        uint4* dst = (uint4*)smem;
        #pragma unroll
        for (int i = 0; i < 8; ++i)
            dst[i * 512 + tid] = src[i * 512 + tid];
        if (tid < 128)
            ((uint4*)(smem + L_C2F))[tid] = ((const uint4*)(ws + WS_C2FIX))[tid];
    }
    __syncthreads();

    const int lpx = wav * 32 + c;        // block-local pixel (0..255)
    const int hw  = hwb + lpx;

    // ---- z fragments: bf16 hi/lo split of -4096*z (R16-verified)
    short8v zh[4], zl[4];
    #pragma unroll
    for (int s = 0; s < 4; ++s) {
        float zf[8];
        #pragma unroll
        for (int j = 0; j < 8; ++j)
            zf[j] = zb[(size_t)(s * 16 + h * 8 + j) * CH_STRIDE + hw];
        short8v vh, vl;
        #pragma unroll
        for (int j = 0; j < 8; ++j) {
            float zs = zf[j] * -4096.0f;
            uint32_t uh = f2bf_rne(zs);
            float l = zs - bf2f((short)uh);
            vh[j] = (short)uh;
            vl[j] = (short)f2bf_rne(l);
        }
        zh[s] = vh; zl[s] = vl;
    }

    // ---- MFMA scores + fixed-point min-track (cb_hi from LDS, cb_lo from L2)
    const float* c2f = (const float*)(smem + L_C2F);
    const short8v* lo_chunks = (const short8v*)(ws + WS_CBLO);
    uint32_t m1 = 0xFFFFFFFFu, m2 = 0xFFFFFFFFu;

    for (int t = 0; t < 16; ++t) {
        int rbase = t * 32 + 4 * h;
        f32x16 acc;
        #pragma unroll
        for (int g = 0; g < 4; ++g) {
            f32x4 q = *(const f32x4*)(c2f + rbase + 8 * g);
            #pragma unroll
            for (int i = 0; i < 4; ++i) acc[4 * g + i] = q[i];
        }
        #pragma unroll
        for (int s = 0; s < 4; ++s) {
            int chunk = (2 * s + h) * KCODES + t * 32 + c;
            short8v a  = *(const short8v*)(smem + L_CBHI + (size_t)chunk * 16);
            short8v al = lo_chunks[chunk];                 // L2-hot, 512B coalesced
            acc = __builtin_amdgcn_mfma_f32_32x32x16_bf16(a,  zh[s], acc, 0, 0, 0);
            acc = __builtin_amdgcn_mfma_f32_32x32x16_bf16(a,  zl[s], acc, 0, 0, 0);
            acc = __builtin_amdgcn_mfma_f32_32x32x16_bf16(al, zh[s], acc, 0, 0, 0);
        }
        #pragma unroll
        for (int i = 0; i < 16; ++i) {
            uint32_t code = (uint32_t)(t * 32 + 4 * h + (i & 3) + 8 * (i >> 2));
            uint32_t u = (((uint32_t)acc[i]) << 9) | code;
            uint32_t mx = m1 > u ? m1 : u;
            m2 = m2 < mx ? m2 : mx;
            m1 = m1 < u ? m1 : u;
        }
    }

    {   // merge lanes l and l^32 (same pixel)
        uint32_t o1 = (uint32_t)__shfl_xor((int)m1, 32);
        uint32_t o2 = (uint32_t)__shfl_xor((int)m2, 32);
        uint32_t mx  = m1 > o1 ? m1 : o1;
        uint32_t mn2 = m2 < o2 ? m2 : o2;
        m2 = mn2 < mx ? mn2 : mx;
        m1 = m1 < o1 ? m1 : o1;
    }

    // provisional idx + flag queue (owner lane h==0)
    if (h == 0) {
        idxs[lpx] = (int)(m1 & 0x1FFu);
        if ((int)((m2 >> 9) - (m1 >> 9)) < MARGIN_UNITS) {
            int pos = atomicAdd(qcnt, 1);
            queue[pos] = lpx;
        }
    }
    __syncthreads();

    // ---- batched exact resolve (R12/R16-verified reference math), 8-wave distributed
    {
        const float* c2r = (const float*)(ws + WS_C2REF);
        const float* cbT = (const float*)(ws + WS_CBT);
        const int nf = *qcnt;
        #pragma unroll 1
        for (int q = wav; q < nf; q += 8) {
            int pl = queue[q];
            int hwq = hwb + pl;
            float a[8] = {0.f,0.f,0.f,0.f,0.f,0.f,0.f,0.f};
            float r[8] = {0.f,0.f,0.f,0.f,0.f,0.f,0.f,0.f};
            #pragma unroll 1
            for (int ib = 0; ib < 8; ++ib) {
                float zr[8];
                #pragma unroll
                for (int i = 0; i < 8; ++i)
                    zr[i] = zb[(size_t)(ib * 8 + i) * CH_STRIDE + hwq];  // uniform, L3-hot
                #pragma unroll
                for (int i = 0; i < 8; ++i) {
                    float zi = zr[i];
                    r[i] += zi * zi;                       // ref pairwise-8 order (i ascending)
                    const float* ct = cbT + (size_t)(ib * 8 + i) * KCODES + lane;
                    #pragma unroll
                    for (int k = 0; k < 8; ++k)
                        a[k] = fmaf(zi, ct[k * 64], a[k]); // ascending i per code
                }
            }
            float A = ((r[0] + r[1]) + (r[2] + r[3])) + ((r[4] + r[5]) + (r[6] + r[7]));
            float best = 3.4e38f; int bidx = 0x7FFFFFFF;
            #pragma unroll
            for (int k = 0; k < 8; ++k) {
                float d = (A - 2.0f * a[k]) + c2r[k * 64 + lane];
                if (d < best) { best = d; bidx = k * 64 + lane; }
            }
            for (int off = 32; off; off >>= 1) {
                float ob = __shfl_down(best, off);
                int   oi = __shfl_down(bidx, off);
                if (ob < best || (ob == best && oi < bidx)) { best = ob; bidx = oi; }
            }
            if (lane == 0) idxs[pl] = bidx;
        }
    }
    __syncthreads();

    // ---- epilogue A: idx out + loss (exact z reloaded from global, L2/L3-hot)
    {
        int idxv = idxs[lpx];
        if (h == 0) out[IDXOUT_OFF + pxblk + lpx] = (float)idxv;
        const float* crow = cb + (size_t)idxv * CDIM;
        float lsum = 0.f;
        #pragma unroll
        for (int s = 0; s < 4; ++s) {
            int ch0 = s * 16 + h * 8;
            f32x4 g0 = *(const f32x4*)(crow + ch0);
            f32x4 g1 = *(const f32x4*)(crow + ch0 + 4);
            #pragma unroll
            for (int j = 0; j < 8; ++j) {
                float zq = (j < 4) ? g0[j] : g1[j - 4];
                float zv = zb[(size_t)(ch0 + j) * CH_STRIDE + hw];
                float d = zq - zv;
                lsum = fmaf(d, d, lsum);
            }
        }
        double dl = (double)lsum;
        for (int off = 32; off; off >>= 1) dl += __shfl_down(dl, off);
        if (lane == 0) wls[wav] = dl;
    }

    // ---- epilogue B: streaming z_q write (1KB contiguous per store across a wave)
    {
        int px0 = lane * 4;                       // 4 consecutive pixels (0..255)
        i32x4 i4 = *(const i32x4*)&idxs[px0];
        float* obase = out + (size_t)b * B_STRIDE + hwb;
        #pragma unroll
        for (int p = 0; p < 8; ++p) {
            int ch = p * 8 + wav;                 // each wave: 8 channels
            f32x4 v;
            v[0] = cb[(size_t)i4[0] * CDIM + ch];
            v[1] = cb[(size_t)i4[1] * CDIM + ch];
            v[2] = cb[(size_t)i4[2] * CDIM + ch];
            v[3] = cb[(size_t)i4[3] * CDIM + ch];
            *(f32x4*)(obase + (size_t)ch * CH_STRIDE + px0) = v;
        }
    }

    __syncthreads();
    if (tid == 0) {
        double s = 0.0;
        #pragma unroll
        for (int i = 0; i < 8; ++i) s += wls[i];
        atomicAdd((double*)ws, s);
    }
}

__global__ void k4_loss(float* __restrict__ out, const double* __restrict__ loss_acc) {
    out[LOSS_OFF] = (float)(1.25 * (*loss_acc) / (double)ZQ_SIZE);
}

extern "C" void kernel_launch(void* const* d_in, const int* in_sizes, int n_in,
                              void* d_out, int out_size, void* d_ws, size_t ws_size,
                              hipStream_t stream) {
    const float* z_e = (const float*)d_in[0];
    const float* cb  = (const float*)d_in[1];
    float* out = (float*)d_out;
    char* ws = (char*)d_ws;

    hipMemsetAsync(ws, 0, 64, stream);
    k0_prep<<<8, 64, 0, stream>>>(cb, ws);
    k1_mfma<<<NPIX / 256, 512, LDS_SZ, stream>>>(z_e, cb, ws, out);
    k4_loss<<<1, 1, 0, stream>>>(out, (const double*)ws);
}

// Round 21
// 85.162 us; speedup vs baseline: 1.1700x; 1.1700x over previous
//
#include <hip/hip_runtime.h>
#include <hip/hip_bf16.h>
#include <stdint.h>

// z_e (32,64,64,64) f32, codebook (512,64) f32.
// d_out (f32): [0..8388607] z_q (B,C,H,W); [8388608] loss; [8388609..] indices as float.
#define NPIX 131072
#define CDIM 64
#define KCODES 512
#define ZQ_SIZE 8388608
#define LOSS_OFF 8388608
#define IDXOUT_OFF 8388609
#define CH_STRIDE 4096
#define B_STRIDE 262144
#define MARGIN_UNITS 512       // 256u ref-grid noise (R5-validated) + 8.5*sigma(30u) f16 err
#define SCALE 4194304.0f       // 2^22
#define BIAS 0.5f

typedef __attribute__((ext_vector_type(8))) _Float16 half8v;  // 8 f16 (4 VGPRs)
typedef __attribute__((ext_vector_type(16))) float f32x16;
typedef __attribute__((ext_vector_type(4))) float f32x4;
typedef __attribute__((ext_vector_type(4))) int i32x4;

// ws layout:
//   0       double loss
//   64      float  c2_ref[512]   (numpy pairwise-8, for exact resolve)
//   2112    float  c2fix[512]    ((||c||^2+0.5)*2^22)
//   4160    ushort cb_f16 chunks [g][code][8 f16], c*2048  (65536 B)
//   69696   float  cbT[64][512]  (131072 B, exact f32 for resolve)
#define WS_C2REF 64
#define WS_C2FIX 2112
#define WS_CBH   4160
#define WS_CBT   69696

// LDS (69.8 KB -> 2 blocks/CU, 16 waves/CU):
#define L_CBH   0          // 65536
#define L_C2F   65536      // 2048
#define L_QUEUE 67584      // int[256]
#define L_QCNT  68608      // int (+pad)
#define L_WLS   68672      // double[8]
#define L_IDXS  68736      // int[256]
#define LDS_SZ  69760

__device__ __forceinline__ unsigned short f2h_bits(float v) {
    _Float16 h = (_Float16)v;            // v_cvt_f16_f32, RNE
    unsigned short u;
    __builtin_memcpy(&u, &h, 2);
    return u;
}

__global__ void k0_prep(const float* __restrict__ cb, char* __restrict__ ws) {
#pragma clang fp contract(off)
    int k = blockIdx.x * 64 + threadIdx.x;
    if (k >= KCODES) return;
    const float* cr = cb + (size_t)k * CDIM;
    float r[8];
    #pragma unroll
    for (int j = 0; j < 8; ++j) r[j] = cr[j] * cr[j];
    #pragma unroll
    for (int t = 1; t < 8; ++t)
        #pragma unroll
        for (int j = 0; j < 8; ++j) r[j] += cr[8 * t + j] * cr[8 * t + j];
    ((float*)(ws + WS_C2REF))[k] = ((r[0] + r[1]) + (r[2] + r[3])) + ((r[4] + r[5]) + (r[6] + r[7]));
    float acc = 0.f;
    #pragma unroll
    for (int i = 0; i < CDIM; ++i) acc = fmaf(cr[i], cr[i], acc);
    ((float*)(ws + WS_C2FIX))[k] = (acc + BIAS) * SCALE;
    unsigned short* hi = (unsigned short*)(ws + WS_CBH);
    #pragma unroll
    for (int g = 0; g < 8; ++g)
        #pragma unroll
        for (int j = 0; j < 8; ++j)
            hi[((size_t)(g * KCODES + k)) * 8 + j] = f2h_bits(cr[g * 8 + j] * 2048.0f);
    float* cbT = (float*)(ws + WS_CBT);
    #pragma unroll
    for (int i = 0; i < CDIM; ++i) cbT[i * KCODES + k] = cr[i];
}

// 512 threads = 8 waves, 256 px/block, grid 512 = 2 blocks/CU (LDS 69.8KB).
// Single f16 MFMA chain: live regs ~48 < 64 -> no spill under the 64 cap.
__global__ __launch_bounds__(512)
void k1_mfma(const float* __restrict__ z_e,
             const float* __restrict__ cb,
             char* __restrict__ ws,
             float* __restrict__ out) {
#pragma clang fp contract(off)
    extern __shared__ char smem[];
    int*    queue = (int*)(smem + L_QUEUE);
    int*    qcnt  = (int*)(smem + L_QCNT);
    double* wls   = (double*)(smem + L_WLS);
    int*    idxs  = (int*)(smem + L_IDXS);

    const int tid  = threadIdx.x;
    const int lane = tid & 63;
    const int wav  = tid >> 6;          // 0..7
    const int h    = lane >> 5;
    const int c    = lane & 31;

    const int pxblk = blockIdx.x * 256;
    const int b     = pxblk >> 12;
    const int hwb   = pxblk & 4095;
    const float* zb = z_e + (size_t)b * B_STRIDE;

    // ---- stage cb_f16 (64KB) + c2fix (2KB) to LDS
    if (tid == 0) *qcnt = 0;
    {
        const uint4* src = (const uint4*)(ws + WS_CBH);
        uint4* dst = (uint4*)smem;
        #pragma unroll
        for (int i = 0; i < 8; ++i)
            dst[i * 512 + tid] = src[i * 512 + tid];
        if (tid < 128)
            ((uint4*)(smem + L_C2F))[tid] = ((const uint4*)(ws + WS_C2FIX))[tid];
    }
    __syncthreads();

    const int lpx = wav * 32 + c;        // block-local pixel (0..255)
    const int hw  = hwb + lpx;

    // ---- z fragments: f16(-4096*z), single chain
    half8v zh[4];
    #pragma unroll
    for (int s = 0; s < 4; ++s) {
        float zf[8];
        #pragma unroll
        for (int j = 0; j < 8; ++j)
            zf[j] = zb[(size_t)(s * 16 + h * 8 + j) * CH_STRIDE + hw];
        half8v vh;
        #pragma unroll
        for (int j = 0; j < 8; ++j)
            vh[j] = (_Float16)(zf[j] * -4096.0f);
        zh[s] = vh;
    }

    // ---- MFMA scores + fixed-point min-track
    const float* c2f = (const float*)(smem + L_C2F);
    uint32_t m1 = 0xFFFFFFFFu, m2 = 0xFFFFFFFFu;

    for (int t = 0; t < 16; ++t) {
        int rbase = t * 32 + 4 * h;
        f32x16 acc;
        #pragma unroll
        for (int g = 0; g < 4; ++g) {
            f32x4 q = *(const f32x4*)(c2f + rbase + 8 * g);
            #pragma unroll
            for (int i = 0; i < 4; ++i) acc[4 * g + i] = q[i];
        }
        #pragma unroll
        for (int s = 0; s < 4; ++s) {
            int chunk = (2 * s + h) * KCODES + t * 32 + c;
            half8v a = *(const half8v*)(smem + L_CBH + (size_t)chunk * 16);
            acc = __builtin_amdgcn_mfma_f32_32x32x16_f16(a, zh[s], acc, 0, 0, 0);
        }
        #pragma unroll
        for (int i = 0; i < 16; ++i) {
            uint32_t code = (uint32_t)(t * 32 + 4 * h + (i & 3) + 8 * (i >> 2));
            uint32_t u = (((uint32_t)acc[i]) << 9) | code;
            uint32_t mx = m1 > u ? m1 : u;
            m2 = m2 < mx ? m2 : mx;
            m1 = m1 < u ? m1 : u;
        }
    }

    {   // merge lanes l and l^32 (same pixel)
        uint32_t o1 = (uint32_t)__shfl_xor((int)m1, 32);
        uint32_t o2 = (uint32_t)__shfl_xor((int)m2, 32);
        uint32_t mx  = m1 > o1 ? m1 : o1;
        uint32_t mn2 = m2 < o2 ? m2 : o2;
        m2 = mn2 < mx ? mn2 : mx;
        m1 = m1 < o1 ? m1 : o1;
    }

    // provisional idx + flag queue (owner lane h==0)
    if (h == 0) {
        idxs[lpx] = (int)(m1 & 0x1FFu);
        if ((int)((m2 >> 9) - (m1 >> 9)) < MARGIN_UNITS) {
            int pos = atomicAdd(qcnt, 1);
            queue[pos] = lpx;
        }
    }
    __syncthreads();

    // ---- batched exact resolve (R12/R16-verified reference math), 8-wave distributed
    {
        const float* c2r = (const float*)(ws + WS_C2REF);
        const float* cbT = (const float*)(ws + WS_CBT);
        const int nf = *qcnt;
        #pragma unroll 1
        for (int q = wav; q < nf; q += 8) {
            int pl = queue[q];
            int hwq = hwb + pl;
            float a[8] = {0.f,0.f,0.f,0.f,0.f,0.f,0.f,0.f};
            float r[8] = {0.f,0.f,0.f,0.f,0.f,0.f,0.f,0.f};
            #pragma unroll 1
            for (int ib = 0; ib < 8; ++ib) {
                float zr[8];
                #pragma unroll
                for (int i = 0; i < 8; ++i)
                    zr[i] = zb[(size_t)(ib * 8 + i) * CH_STRIDE + hwq];  // uniform, L3-hot
                #pragma unroll
                for (int i = 0; i < 8; ++i) {
                    float zi = zr[i];
                    r[i] += zi * zi;                       // ref pairwise-8 order (i ascending)
                    const float* ct = cbT + (size_t)(ib * 8 + i) * KCODES + lane;
                    #pragma unroll
                    for (int k = 0; k < 8; ++k)
                        a[k] = fmaf(zi, ct[k * 64], a[k]); // ascending i per code
                }
            }
            float A = ((r[0] + r[1]) + (r[2] + r[3])) + ((r[4] + r[5]) + (r[6] + r[7]));
            float best = 3.4e38f; int bidx = 0x7FFFFFFF;
            #pragma unroll
            for (int k = 0; k < 8; ++k) {
                float d = (A - 2.0f * a[k]) + c2r[k * 64 + lane];
                if (d < best) { best = d; bidx = k * 64 + lane; }
            }
            for (int off = 32; off; off >>= 1) {
                float ob = __shfl_down(best, off);
                int   oi = __shfl_down(bidx, off);
                if (ob < best || (ob == best && oi < bidx)) { best = ob; bidx = oi; }
            }
            if (lane == 0) idxs[pl] = bidx;
        }
    }
    __syncthreads();

    // ---- epilogue A: idx out + loss (z reconstructed from zh f16: R18-validated)
    {
        int idxv = idxs[lpx];
        if (h == 0) out[IDXOUT_OFF + pxblk + lpx] = (float)idxv;
        const float* crow = cb + (size_t)idxv * CDIM;
        float lsum = 0.f;
        #pragma unroll
        for (int s = 0; s < 4; ++s) {
            int ch0 = s * 16 + h * 8;
            f32x4 g0 = *(const f32x4*)(crow + ch0);
            f32x4 g1 = *(const f32x4*)(crow + ch0 + 4);
            #pragma unroll
            for (int j = 0; j < 8; ++j) {
                float zq = (j < 4) ? g0[j] : g1[j - 4];
                float zv = (float)zh[s][j] * -2.44140625e-4f;
                float d = zq - zv;
                lsum = fmaf(d, d, lsum);
            }
        }
        double dl = (double)lsum;
        for (int off = 32; off; off >>= 1) dl += __shfl_down(dl, off);
        if (lane == 0) wls[wav] = dl;
    }

    // ---- epilogue B: streaming z_q write (1KB contiguous per store across a wave)
    {
        int px0 = lane * 4;                       // 4 consecutive pixels (0..255)
        i32x4 i4 = *(const i32x4*)&idxs[px0];
        float* obase = out + (size_t)b * B_STRIDE + hwb;
        #pragma unroll
        for (int p = 0; p < 8; ++p) {
            int ch = p * 8 + wav;                 // each wave: 8 channels
            f32x4 v;
            v[0] = cb[(size_t)i4[0] * CDIM + ch];
            v[1] = cb[(size_t)i4[1] * CDIM + ch];
            v[2] = cb[(size_t)i4[2] * CDIM + ch];
            v[3] = cb[(size_t)i4[3] * CDIM + ch];
            *(f32x4*)(obase + (size_t)ch * CH_STRIDE + px0) = v;
        }
    }

    __syncthreads();
    if (tid == 0) {
        double s = 0.0;
        #pragma unroll
        for (int i = 0; i < 8; ++i) s += wls[i];
        atomicAdd((double*)ws, s);
    }
}

__global__ void k4_loss(float* __restrict__ out, const double* __restrict__ loss_acc) {
    out[LOSS_OFF] = (float)(1.25 * (*loss_acc) / (double)ZQ_SIZE);
}

extern "C" void kernel_launch(void* const* d_in, const int* in_sizes, int n_in,
                              void* d_out, int out_size, void* d_ws, size_t ws_size,
                              hipStream_t stream) {
    const float* z_e = (const float*)d_in[0];
    const float* cb  = (const float*)d_in[1];
    float* out = (float*)d_out;
    char* ws = (char*)d_ws;

    hipMemsetAsync(ws, 0, 64, stream);
    k0_prep<<<8, 64, 0, stream>>>(cb, ws);
    k1_mfma<<<NPIX / 256, 512, LDS_SZ, stream>>>(z_e, cb, ws, out);
    k4_loss<<<1, 1, 0, stream>>>(out, (const double*)ws);
}